// Round 7
// baseline (12844.713 us; speedup 1.0000x reference)
//
#include <hip/hip_runtime.h>
#include <math.h>

// Problem constants
#define DD   512
#define LSEQ 2048
#define NBAT 16
#define RTOT (NBAT * LSEQ)   // 32768 rows

typedef __attribute__((ext_vector_type(8))) short bf16x8;
typedef __attribute__((ext_vector_type(4))) float f32x4;

#define AS1(p) ((const __attribute__((address_space(1))) void*)(p))
#define AS3(p) ((__attribute__((address_space(3))) void*)(p))
#define MFMA16 __builtin_amdgcn_mfma_f32_16x16x32_bf16

__device__ __forceinline__ unsigned short f2bf(float f) {
  unsigned u = __builtin_bit_cast(unsigned, f);
  u += 0x7fffu + ((u >> 16) & 1u);
  return (unsigned short)(u >> 16);
}

// h LDS swizzle: element (m,n) at short-index m*512 + (n ^ ((m&7)<<3))
#define SWZH(m, n) ((m) * 512u + ((n) ^ (((m) & 7u) << 3)))

// ---------------------------------------------------------------------------
// prep: fold BN into Wx (Wx' = Wx*diag(inv), b' = Wx(beta-mean*iv)+b_rnn),
// convert Wffn and Wh to bf16.
// blocks 0..511: Wx'+b' ; 512..1535: Wffn ; 1536..2047: Wh.
// ---------------------------------------------------------------------------
__global__ __launch_bounds__(256) void prep_kernel(
    const float* __restrict__ Wx, const float* __restrict__ gamma,
    const float* __restrict__ beta, const float* __restrict__ mean,
    const float* __restrict__ var, const float* __restrict__ brnn,
    const float* __restrict__ Wffn, const float* __restrict__ Wh,
    unsigned short* __restrict__ Wxp, unsigned short* __restrict__ Wfb,
    unsigned short* __restrict__ Whb, float* __restrict__ bprime)
{
  const unsigned tid = threadIdx.x, bx = blockIdx.x;
  if (bx < 512) {
    __shared__ float red[256];
    float partial = 0.f;
#pragma unroll
    for (int i = 0; i < 2; ++i) {
      unsigned d = i * 256u + tid;
      float iv = gamma[d] * rsqrtf(var[d] + 1e-5f);
      float w  = Wx[bx * 512u + d];
      Wxp[bx * 512u + d] = (unsigned short)f2bf(w * iv);
      partial += w * (beta[d] - mean[d] * iv);
    }
    red[tid] = partial; __syncthreads();
    for (unsigned s = 128; s > 0; s >>= 1) {
      if (tid < s) red[tid] += red[tid + s];
      __syncthreads();
    }
    if (tid == 0) bprime[bx] = red[0] + brnn[bx];
  } else if (bx < 1536) {
    unsigned row = bx - 512;
#pragma unroll
    for (int i = 0; i < 2; ++i) {
      unsigned d = i * 256u + tid;
      Wfb[row * 512u + d] = (unsigned short)f2bf(Wffn[row * 512u + d]);
    }
  } else {
    unsigned row = bx - 1536;
#pragma unroll
    for (int i = 0; i < 2; ++i) {
      unsigned d = i * 256u + tid;
      Whb[row * 512u + d] = (unsigned short)f2bf(Wh[row * 512u + d]);
    }
  }
}

// ---------------------------------------------------------------------------
// convert x (fp32) -> bf16, row-major (RTOT, D)
// ---------------------------------------------------------------------------
__global__ __launch_bounds__(256) void convx_kernel(
    const float* __restrict__ x, unsigned short* __restrict__ Xbf)
{
  const unsigned total4 = RTOT * DD / 4;
  unsigned i = blockIdx.x * 256u + threadIdx.x;
  const unsigned stride = gridDim.x * 256u;
  const float4* __restrict__ x4 = (const float4*)x;
  for (; i < total4; i += stride) {
    float4 v = x4[i];
    unsigned short o0 = f2bf(v.x), o1 = f2bf(v.y), o2 = f2bf(v.z), o3 = f2bf(v.w);
    unsigned long long pack = (unsigned long long)o0 |
                              ((unsigned long long)o1 << 16) |
                              ((unsigned long long)o2 << 32) |
                              ((unsigned long long)o3 << 48);
    *(unsigned long long*)(Xbf + i * 4u) = pack;
  }
}

// ---------------------------------------------------------------------------
// GEMM1: Ubf[r,e] = bf16( sum_d Xbf[r,d]*Wxp[e,d] + b'[e] )   (into d_out lo)
// ---------------------------------------------------------------------------
__global__ __launch_bounds__(256) void gemm_u_kernel(
    const unsigned short* __restrict__ A, const unsigned short* __restrict__ Bw,
    const float* __restrict__ bias, unsigned short* __restrict__ Ubf)
{
  __shared__ __align__(16) unsigned char lds[16384]; // A 8KB | B 8KB
  const unsigned tid = threadIdx.x;
  const unsigned lid = tid & 63u, wid = tid >> 6;
  const unsigned wr = wid >> 1, wc = wid & 1u;
  const unsigned rbase = blockIdx.x * 128u, nbase = blockIdx.y * 128u;

  f32x4 acc[4][4] = {};
  for (int kt = 0; kt < 16; ++kt) {
    __syncthreads();
#pragma unroll
    for (int i = 0; i < 2; ++i) {
      unsigned c = i * 256u + tid;
      const unsigned short* g = A + (rbase + (c >> 2)) * 512u + kt * 32u + (c & 3u) * 8u;
      __builtin_amdgcn_global_load_lds(AS1(g), AS3(lds + c * 16u), 16, 0, 0);
    }
#pragma unroll
    for (int i = 0; i < 2; ++i) {
      unsigned c = i * 256u + tid;
      const unsigned short* g = Bw + (nbase + (c >> 2)) * 512u + kt * 32u + (c & 3u) * 8u;
      __builtin_amdgcn_global_load_lds(AS1(g), AS3(lds + 8192u + c * 16u), 16, 0, 0);
    }
    __syncthreads();
    bf16x8 af[4], bfr[4];
#pragma unroll
    for (int mi = 0; mi < 4; ++mi)
      af[mi] = *(const bf16x8*)(lds + (wr * 64u + mi * 16u + (lid & 15u)) * 64u + (lid >> 4) * 16u);
#pragma unroll
    for (int ni = 0; ni < 4; ++ni)
      bfr[ni] = *(const bf16x8*)(lds + 8192u + (wc * 64u + ni * 16u + (lid & 15u)) * 64u + (lid >> 4) * 16u);
#pragma unroll
    for (int mi = 0; mi < 4; ++mi)
#pragma unroll
      for (int ni = 0; ni < 4; ++ni)
        acc[mi][ni] = MFMA16(af[mi], bfr[ni], acc[mi][ni], 0, 0, 0);
  }
#pragma unroll
  for (int mi = 0; mi < 4; ++mi)
#pragma unroll
    for (int ni = 0; ni < 4; ++ni) {
      unsigned e = nbase + wc * 64u + ni * 16u + (lid & 15u);
      float bb = bias[e];
#pragma unroll
      for (int j = 0; j < 4; ++j) {
        unsigned r = rbase + wr * 64u + mi * 16u + (lid >> 4) * 4u + j;
        Ubf[r * 512u + e] = f2bf(acc[mi][ni][j] + bb);
      }
    }
}

// ---------------------------------------------------------------------------
// Recurrence, SINGLE-CU edition: 1 workgroup x 512 threads (8 waves), zero
// inter-WG sync. Wave w owns cols [w*64, w*64+64) = 4 MFMA tiles, M=16.
// Wh split: chunks 0..8 (k<288) stationary in VGPRs (144/lane);
//           chunks 9..11 (k 288..384) in LDS (96KB, chunk-XOR swizzled);
//           chunks 12..15 (k 384..512) streamed from L2 each step (128KB).
// h: 2x16KB LDS double-buffer, XOR-swizzled. u: bf16, prefetched 1 step ahead.
// Per-step barrier = lgkmcnt(0)+s_barrier (no vmcnt drain: u loads and Hs
// stores ride across steps).
// ---------------------------------------------------------------------------
__global__ __launch_bounds__(512) void rnn_rec_kernel(
    const unsigned short* __restrict__ Whb,
    const unsigned short* __restrict__ Ubf,
    unsigned short* __restrict__ Hs)
{
  __shared__ unsigned short hbuf[2][8192];   // [buf][SWZH(m,n)]
  __shared__ unsigned short whs[49152];      // [n*96 + chunk-swz], k 288..384

  const unsigned tid = threadIdx.x, lid = tid & 63u, w = tid >> 6;
  const unsigned m0 = lid >> 4, ln = lid & 15u;
  const unsigned nb = w * 64u;

  // init: h0 = 0, stage Wh k-range [288,384) into LDS (chunk-internal swizzle)
  for (unsigned i = tid; i < 8192u; i += 512u) hbuf[0][i] = 0;
  for (unsigned i = tid; i < 49152u; i += 512u) {
    unsigned n = i / 96u, kk = i % 96u;
    unsigned c = kk >> 5, ko = kk & 31u;
    unsigned idx = n * 96u + c * 32u + (((ko & 24u) ^ ((n & 3u) << 3)) | (ko & 7u));
    whs[idx] = Whb[n * 512u + 288u + kk];
  }

  // stationary B fragments: chunks 0..8
  bf16x8 bo[9][4];
#pragma unroll
  for (int c = 0; c < 9; ++c)
#pragma unroll
    for (int nt = 0; nt < 4; ++nt)
      bo[c][nt] = *(const bf16x8*)(Whb + (nb + nt * 16u + ln) * 512u + c * 32u + m0 * 8u);

  // u prefetch for step 1 (t=0)
  unsigned short uu[16];
#pragma unroll
  for (int nt = 0; nt < 4; ++nt)
#pragma unroll
    for (int j = 0; j < 4; ++j)
      uu[nt * 4 + j] = Ubf[((m0 * 4u + j) * (unsigned)LSEQ) * 512u + nb + nt * 16u + ln];

  __syncthreads();

  unsigned cur = 0;
  for (unsigned st = 1; st <= (unsigned)LSEQ; ++st) {
    const unsigned short* hb = hbuf[cur];
    unsigned short* hn = hbuf[cur ^ 1u];

    // prefetch streamed chunk 12 (k 384..416) from L2
    bf16x8 bsA[4], bsB[4];
#pragma unroll
    for (int nt = 0; nt < 4; ++nt)
      bsA[nt] = *(const bf16x8*)(Whb + (nb + nt * 16u + ln) * 512u + 384u + m0 * 8u);

    f32x4 acc[4] = {};

    // stationary chunks 0..8
#pragma unroll
    for (int c = 0; c < 9; ++c) {
      bf16x8 a = *(const bf16x8*)(hb + SWZH(ln, (unsigned)c * 32u + m0 * 8u));
#pragma unroll
      for (int nt = 0; nt < 4; ++nt)
        acc[nt] = MFMA16(a, bo[c][nt], acc[nt], 0, 0, 0);
    }

    // prefetch streamed chunk 13 (k 416..448)
#pragma unroll
    for (int nt = 0; nt < 4; ++nt)
      bsB[nt] = *(const bf16x8*)(Whb + (nb + nt * 16u + ln) * 512u + 416u + m0 * 8u);

    // LDS chunks 9..11 (k 288..384)
#pragma unroll
    for (int c = 0; c < 3; ++c) {
      bf16x8 a = *(const bf16x8*)(hb + SWZH(ln, 288u + (unsigned)c * 32u + m0 * 8u));
      bf16x8 bl[4];
#pragma unroll
      for (int nt = 0; nt < 4; ++nt) {
        unsigned n = nb + nt * 16u + ln;
        unsigned idx = n * 96u + (unsigned)c * 32u + ((m0 * 8u) ^ ((n & 3u) << 3));
        bl[nt] = *(const bf16x8*)(whs + idx);
      }
#pragma unroll
      for (int nt = 0; nt < 4; ++nt)
        acc[nt] = MFMA16(a, bl[nt], acc[nt], 0, 0, 0);
    }

    // streamed chunk 12 compute; prefetch 14
    {
      bf16x8 a = *(const bf16x8*)(hb + SWZH(ln, 384u + m0 * 8u));
#pragma unroll
      for (int nt = 0; nt < 4; ++nt)
        acc[nt] = MFMA16(a, bsA[nt], acc[nt], 0, 0, 0);
    }
#pragma unroll
    for (int nt = 0; nt < 4; ++nt)
      bsA[nt] = *(const bf16x8*)(Whb + (nb + nt * 16u + ln) * 512u + 448u + m0 * 8u);

    // streamed chunk 13 compute; prefetch 15
    {
      bf16x8 a = *(const bf16x8*)(hb + SWZH(ln, 416u + m0 * 8u));
#pragma unroll
      for (int nt = 0; nt < 4; ++nt)
        acc[nt] = MFMA16(a, bsB[nt], acc[nt], 0, 0, 0);
    }
#pragma unroll
    for (int nt = 0; nt < 4; ++nt)
      bsB[nt] = *(const bf16x8*)(Whb + (nb + nt * 16u + ln) * 512u + 480u + m0 * 8u);

    // streamed chunks 14, 15 compute
    {
      bf16x8 a = *(const bf16x8*)(hb + SWZH(ln, 448u + m0 * 8u));
#pragma unroll
      for (int nt = 0; nt < 4; ++nt)
        acc[nt] = MFMA16(a, bsA[nt], acc[nt], 0, 0, 0);
    }
    {
      bf16x8 a = *(const bf16x8*)(hb + SWZH(ln, 480u + m0 * 8u));
#pragma unroll
      for (int nt = 0; nt < 4; ++nt)
        acc[nt] = MFMA16(a, bsB[nt], acc[nt], 0, 0, 0);
    }

    // u add + tanh -> h16; write h[nxt] (LDS, swizzled)
    unsigned short h16[16];
#pragma unroll
    for (int nt = 0; nt < 4; ++nt)
#pragma unroll
      for (int j = 0; j < 4; ++j) {
        float u = __builtin_bit_cast(float, (unsigned)uu[nt * 4 + j] << 16);
        float s = acc[nt][j] + u;
        float e2 = __expf(2.f * s);
        float h = 1.f - 2.f / (e2 + 1.f);     // tanh(s)
        unsigned short hv = f2bf(h);
        h16[nt * 4 + j] = hv;
        hn[SWZH(m0 * 4u + j, nb + nt * 16u + ln)] = hv;
      }

    // Hs history stores (fire-and-forget) + next-u prefetch (ride past barrier)
    const unsigned t = st - 1u;
#pragma unroll
    for (int nt = 0; nt < 4; ++nt)
#pragma unroll
      for (int j = 0; j < 4; ++j)
        Hs[((m0 * 4u + j) * (unsigned)LSEQ + t) * 512u + nb + nt * 16u + ln] = h16[nt * 4 + j];

    const unsigned tn = (st < (unsigned)LSEQ) ? st : ((unsigned)LSEQ - 1u);
#pragma unroll
    for (int nt = 0; nt < 4; ++nt)
#pragma unroll
      for (int j = 0; j < 4; ++j)
        uu[nt * 4 + j] = Ubf[((m0 * 4u + j) * (unsigned)LSEQ + tn) * 512u + nb + nt * 16u + ln];

    // barrier WITHOUT vmcnt drain: only LDS ops must complete
    asm volatile("s_waitcnt lgkmcnt(0)" ::: "memory");
    __builtin_amdgcn_sched_barrier(0);
    __builtin_amdgcn_s_barrier();
    __builtin_amdgcn_sched_barrier(0);

    cur ^= 1u;
  }
}

// ---------------------------------------------------------------------------
// GEMM3 + GLU + residual: Y[r,e]=sum_d Hs[r,d]*Wfb[e,d]+bffn[e]; paired g-tile
// at e+512; out[r,e] = a*sigmoid(g) + x[r,e]  (fp32, overwrites d_out)
// ---------------------------------------------------------------------------
__global__ __launch_bounds__(256) void gemm_ffn_kernel(
    const unsigned short* __restrict__ A, const unsigned short* __restrict__ Bw,
    const float* __restrict__ bffn, const float* __restrict__ x,
    float* __restrict__ out)
{
  __shared__ __align__(16) unsigned char lds[24576]; // A 8KB | Ba 8KB | Bg 8KB
  const unsigned tid = threadIdx.x;
  const unsigned lid = tid & 63u, wid = tid >> 6;
  const unsigned wr = wid >> 1, wc = wid & 1u;
  const unsigned rbase = blockIdx.x * 128u, nbase = blockIdx.y * 128u;

  f32x4 acc_a[4][4] = {}, acc_g[4][4] = {};
  for (int kt = 0; kt < 16; ++kt) {
    __syncthreads();
#pragma unroll
    for (int i = 0; i < 2; ++i) {
      unsigned c = i * 256u + tid;
      const unsigned short* ga = A + (rbase + (c >> 2)) * 512u + kt * 32u + (c & 3u) * 8u;
      __builtin_amdgcn_global_load_lds(AS1(ga), AS3(lds + c * 16u), 16, 0, 0);
      const unsigned short* gb = Bw + (nbase + (c >> 2)) * 512u + kt * 32u + (c & 3u) * 8u;
      __builtin_amdgcn_global_load_lds(AS1(gb), AS3(lds + 8192u + c * 16u), 16, 0, 0);
      const unsigned short* gg = Bw + (512u + nbase + (c >> 2)) * 512u + kt * 32u + (c & 3u) * 8u;
      __builtin_amdgcn_global_load_lds(AS1(gg), AS3(lds + 16384u + c * 16u), 16, 0, 0);
    }
    __syncthreads();
    bf16x8 af[4], ba[4], bg[4];
#pragma unroll
    for (int mi = 0; mi < 4; ++mi)
      af[mi] = *(const bf16x8*)(lds + (wr * 64u + mi * 16u + (lid & 15u)) * 64u + (lid >> 4) * 16u);
#pragma unroll
    for (int ni = 0; ni < 4; ++ni) {
      ba[ni] = *(const bf16x8*)(lds + 8192u  + (wc * 64u + ni * 16u + (lid & 15u)) * 64u + (lid >> 4) * 16u);
      bg[ni] = *(const bf16x8*)(lds + 16384u + (wc * 64u + ni * 16u + (lid & 15u)) * 64u + (lid >> 4) * 16u);
    }
#pragma unroll
    for (int mi = 0; mi < 4; ++mi)
#pragma unroll
      for (int ni = 0; ni < 4; ++ni) {
        acc_a[mi][ni] = MFMA16(af[mi], ba[ni], acc_a[mi][ni], 0, 0, 0);
        acc_g[mi][ni] = MFMA16(af[mi], bg[ni], acc_g[mi][ni], 0, 0, 0);
      }
  }
#pragma unroll
  for (int mi = 0; mi < 4; ++mi)
#pragma unroll
    for (int ni = 0; ni < 4; ++ni) {
      unsigned e = nbase + wc * 64u + ni * 16u + (lid & 15u);
      float bba = bffn[e], bbg = bffn[e + 512u];
#pragma unroll
      for (int j = 0; j < 4; ++j) {
        unsigned r = rbase + wr * 64u + mi * 16u + (lid >> 4) * 4u + j;
        float a  = acc_a[mi][ni][j] + bba;
        float gg = acc_g[mi][ni][j] + bbg;
        float sg = 1.f / (1.f + __expf(-gg));
        out[r * 512u + e] = a * sg + x[r * 512u + e];
      }
    }
}

// ---------------------------------------------------------------------------
extern "C" void kernel_launch(void* const* d_in, const int* in_sizes, int n_in,
                              void* d_out, int out_size, void* d_ws, size_t ws_size,
                              hipStream_t stream) {
  const float* x     = (const float*)d_in[0];
  const float* gamma = (const float*)d_in[1];
  const float* beta  = (const float*)d_in[2];
  const float* mean  = (const float*)d_in[3];
  const float* var   = (const float*)d_in[4];
  const float* Wx    = (const float*)d_in[5];
  const float* Wh    = (const float*)d_in[6];
  const float* brnn  = (const float*)d_in[7];
  const float* Wffn  = (const float*)d_in[8];
  const float* bffn  = (const float*)d_in[9];
  float* out = (float*)d_out;

  // workspace layout
  unsigned char* ws = (unsigned char*)d_ws;
  unsigned short* Hs   = (unsigned short*)(ws);                     // 32 MB
  unsigned short* Xbf  = (unsigned short*)(ws + (size_t)33554432);  // 32 MB
  unsigned short* Wxp  = (unsigned short*)(ws + (size_t)67108864);  // 512 KB
  unsigned short* Wfb  = (unsigned short*)(ws + (size_t)67633152);  // 1 MB
  unsigned short* Whb  = (unsigned short*)(ws + (size_t)68681728);  // 512 KB
  float*          bpr  = (float*)        (ws + (size_t)69206016);   // 2 KB

  // Ubf (bf16 input projection, 32MB) lives in d_out's first half; dead once
  // rnn_rec finishes, then gemm_ffn overwrites all of d_out with fp32 output.
  unsigned short* Ubf = (unsigned short*)d_out;

  prep_kernel<<<2048, 256, 0, stream>>>(Wx, gamma, beta, mean, var, brnn,
                                        Wffn, Wh, Wxp, Wfb, Whb, bpr);
  convx_kernel<<<2048, 256, 0, stream>>>(x, Xbf);
  gemm_u_kernel<<<dim3(256, 4), 256, 0, stream>>>(Xbf, Wxp, bpr, Ubf);
  rnn_rec_kernel<<<1, 512, 0, stream>>>(Whb, Ubf, Hs);
  gemm_ffn_kernel<<<dim3(256, 4), 256, 0, stream>>>(Hs, Wfb, bffn, x, out);
}